// Round 1
// baseline (683.125 us; speedup 1.0000x reference)
//
#include <hip/hip_runtime.h>

#define NN 51681
#define EE 2048
#define Z_OFF (51681LL * 2048LL)

// ---------------- degree / norm prep ----------------

__global__ void deg_init_k(float* __restrict__ deg) {
    int i = blockIdx.x * 256 + threadIdx.x;
    if (i < NN) deg[i] = 1.0f;   // self-loop weight
}

__global__ void deg_scatter_k(const int* __restrict__ dst, const float* __restrict__ w,
                              float* __restrict__ deg) {
    int e = blockIdx.x * 256 + threadIdx.x;
    if (e < EE) atomicAdd(&deg[dst[e]], w[e]);
}

__global__ void norm_edge_k(const int* __restrict__ src, const int* __restrict__ dst,
                            const float* __restrict__ w, const float* __restrict__ deg,
                            float* __restrict__ nrm) {
    int e = blockIdx.x * 256 + threadIdx.x;
    if (e < EE) nrm[e] = rsqrtf(deg[src[e]]) * w[e] * rsqrtf(deg[dst[e]]);
}

// ---------------- aggregation: A = Ahat * X ----------------
// self part: A[j] = X[j] / deg[j]   (dinv[j]^2 == 1/deg[j])

template<int FIN>
__global__ void agg_self_k(const float* __restrict__ X, const float* __restrict__ deg,
                           float* __restrict__ A) {
    constexpr int F4 = FIN / 4;
    int tid = blockIdx.x * 256 + threadIdx.x;
    if (tid >= NN * F4) return;
    int j = tid / F4;
    float s = 1.0f / deg[j];
    float4 v = reinterpret_cast<const float4*>(X)[tid];
    reinterpret_cast<float4*>(A)[tid] = make_float4(v.x * s, v.y * s, v.z * s, v.w * s);
}

template<int FIN>
__global__ void edge_scatter_k(const int* __restrict__ src, const int* __restrict__ dst,
                               const float* __restrict__ nrm, const float* __restrict__ X,
                               float* __restrict__ A) {
    constexpr int F4 = FIN / 4;
    int tid = blockIdx.x * 256 + threadIdx.x;
    if (tid >= EE * F4) return;
    int e = tid / F4;
    int f = (tid - e * F4) * 4;
    float n = nrm[e];
    const float4 v = *reinterpret_cast<const float4*>(&X[(long long)src[e] * FIN + f]);
    float* a = &A[(long long)dst[e] * FIN + f];
    atomicAdd(a + 0, n * v.x);
    atomicAdd(a + 1, n * v.y);
    atomicAdd(a + 2, n * v.z);
    atomicAdd(a + 3, n * v.w);
}

// ---------------- small GEMM: out[N,FOUT] = act(A[N,K] @ W[K,FOUT] + b) ----------------

template<int K, int FOUT, bool RELU>
__global__ __launch_bounds__(256) void gemm_small_k(
    const float* __restrict__ A, const float* __restrict__ W,
    const float* __restrict__ bias, float* __restrict__ out) {
    constexpr int NPB = 256 / FOUT;     // nodes per block
    __shared__ float Ws[K * FOUT];
    __shared__ float As[NPB][K];
    __shared__ float bs[FOUT];
    int tid = threadIdx.x;
    for (int i = tid; i < K * FOUT / 4; i += 256)
        reinterpret_cast<float4*>(Ws)[i] = reinterpret_cast<const float4*>(W)[i];
    if (tid < FOUT) bs[tid] = bias[tid];
    int node0 = blockIdx.x * NPB;
    for (int i = tid; i < NPB * (K / 4); i += 256) {
        int r = i / (K / 4);
        int kk = (i - r * (K / 4)) * 4;
        int g = node0 + r;
        float4 v = make_float4(0.f, 0.f, 0.f, 0.f);
        if (g < NN) v = *reinterpret_cast<const float4*>(&A[(long long)g * K + kk]);
        *reinterpret_cast<float4*>(&As[r][kk]) = v;
    }
    __syncthreads();
    int ln = tid / FOUT;
    int n  = tid - ln * FOUT;
    int g = node0 + ln;
    if (g >= NN) return;
    float s = bs[n];
    #pragma unroll
    for (int k = 0; k < K; ++k)
        s = fmaf(As[ln][k], Ws[k * FOUT + n], s);
    if (RELU) s = fmaxf(s, 0.f);
    out[(long long)g * FOUT + n] = s;
}

// ---------------- big GEMM: out[N,2048] = A[N,64] @ W[64,2048] + b ----------------
// BM=BN=64, K=64 fully resident in LDS (single load phase). 256 thr, 4x4 microtile.

__global__ __launch_bounds__(256) void gemm_big_k(
    const float* __restrict__ A,    // [NN,64]
    const float* __restrict__ W,    // [64,2048]
    const float* __restrict__ bias, // [2048]
    float* __restrict__ out) {      // [NN,2048]
    __shared__ float As[64][68];    // pad 68: row-reads land on 2 banks -> free 2-way
    __shared__ float Bs[64][68];
    int tid = threadIdx.x;
    int row0 = blockIdx.x * 64;
    int col0 = blockIdx.y * 64;
    #pragma unroll
    for (int i = 0; i < 4; ++i) {
        int f4 = i * 256 + tid;
        int r = f4 >> 4;
        int kk = (f4 & 15) << 2;
        int gr = row0 + r;
        float4 v = make_float4(0.f, 0.f, 0.f, 0.f);
        if (gr < NN) v = *reinterpret_cast<const float4*>(&A[(long long)gr * 64 + kk]);
        *reinterpret_cast<float4*>(&As[r][kk]) = v;
    }
    #pragma unroll
    for (int i = 0; i < 4; ++i) {
        int f4 = i * 256 + tid;
        int k = f4 >> 4;
        int cc = (f4 & 15) << 2;
        float4 v = *reinterpret_cast<const float4*>(&W[k * 2048 + col0 + cc]);
        *reinterpret_cast<float4*>(&Bs[k][cc]) = v;
    }
    __syncthreads();
    int tx = tid & 15, ty = tid >> 4;
    float4 bb = *reinterpret_cast<const float4*>(&bias[col0 + tx * 4]);
    float c[4][4];
    #pragma unroll
    for (int i = 0; i < 4; ++i) { c[i][0] = bb.x; c[i][1] = bb.y; c[i][2] = bb.z; c[i][3] = bb.w; }
    #pragma unroll
    for (int k = 0; k < 64; k += 4) {
        float4 a[4], b[4];
        #pragma unroll
        for (int i = 0; i < 4; ++i) a[i] = *reinterpret_cast<const float4*>(&As[ty * 4 + i][k]);
        #pragma unroll
        for (int kk = 0; kk < 4; ++kk) b[kk] = *reinterpret_cast<const float4*>(&Bs[k + kk][tx * 4]);
        #pragma unroll
        for (int i = 0; i < 4; ++i) {
            const float av[4] = {a[i].x, a[i].y, a[i].z, a[i].w};
            #pragma unroll
            for (int kk = 0; kk < 4; ++kk) {
                c[i][0] = fmaf(av[kk], b[kk].x, c[i][0]);
                c[i][1] = fmaf(av[kk], b[kk].y, c[i][1]);
                c[i][2] = fmaf(av[kk], b[kk].z, c[i][2]);
                c[i][3] = fmaf(av[kk], b[kk].w, c[i][3]);
            }
        }
    }
    #pragma unroll
    for (int i = 0; i < 4; ++i) {
        int gr = row0 + ty * 4 + i;
        if (gr < NN)
            *reinterpret_cast<float4*>(&out[(long long)gr * 2048 + col0 + tx * 4]) =
                make_float4(c[i][0], c[i][1], c[i][2], c[i][3]);
    }
}

// ---------------- launch ----------------

extern "C" void kernel_launch(void* const* d_in, const int* in_sizes, int n_in,
                              void* d_out, int out_size, void* d_ws, size_t ws_size,
                              hipStream_t stream) {
    const int*   edge_index = (const int*)d_in[0];   // [2, EE]
    const int*   src = edge_index;
    const int*   dst = edge_index + EE;
    const float* ew  = (const float*)d_in[1];
    const float* emb = (const float*)d_in[2];        // [NN,32]
    const float* W1  = (const float*)d_in[3];        // [32,64]
    const float* b1  = (const float*)d_in[4];
    const float* W2  = (const float*)d_in[5];        // [64,32]
    const float* b2  = (const float*)d_in[6];
    const float* W3  = (const float*)d_in[7];        // [32,64]
    const float* b3  = (const float*)d_in[8];
    const float* W4  = (const float*)d_in[9];        // [64,2048]
    const float* b4  = (const float*)d_in[10];

    float* out = (float*)d_out;                      // recon_x [NN,2048]
    float* z   = out + Z_OFF;                        // z [NN,32]

    float* ws  = (float*)d_ws;
    float* deg = ws;                                 // NN floats
    float* nrm = ws + 51684;                         // EE floats (16B-aligned)
    float* t0  = ws + 53732;                         // NN*64 (agg buffer)
    float* t1  = t0 + 3307584;                       // NN*64 (layer output)

    // normalization (shared by all 4 layers)
    deg_init_k<<<(NN + 255) / 256, 256, 0, stream>>>(deg);
    deg_scatter_k<<<(EE + 255) / 256, 256, 0, stream>>>(dst, ew, deg);
    norm_edge_k<<<(EE + 255) / 256, 256, 0, stream>>>(src, dst, ew, deg, nrm);

    // Layer 1: emb[N,32] -> x1 = relu((Ahat emb) W1 + b1) in t1[N,64]
    agg_self_k<32><<<(NN * 8 + 255) / 256, 256, 0, stream>>>(emb, deg, t0);
    edge_scatter_k<32><<<(EE * 8 + 255) / 256, 256, 0, stream>>>(src, dst, nrm, emb, t0);
    gemm_small_k<32, 64, true><<<(NN + 3) / 4, 256, 0, stream>>>(t0, W1, b1, t1);

    // Layer 2: t1[N,64] -> z = relu((Ahat x1) W2 + b2) in d_out z-region [N,32]
    agg_self_k<64><<<(NN * 16 + 255) / 256, 256, 0, stream>>>(t1, deg, t0);
    edge_scatter_k<64><<<(EE * 16 + 255) / 256, 256, 0, stream>>>(src, dst, nrm, t1, t0);
    gemm_small_k<64, 32, true><<<(NN + 7) / 8, 256, 0, stream>>>(t0, W2, b2, z);

    // Layer 3: z[N,32] -> h = relu((Ahat z) W3 + b3) in t1[N,64]
    agg_self_k<32><<<(NN * 8 + 255) / 256, 256, 0, stream>>>(z, deg, t0);
    edge_scatter_k<32><<<(EE * 8 + 255) / 256, 256, 0, stream>>>(src, dst, nrm, z, t0);
    gemm_small_k<32, 64, true><<<(NN + 3) / 4, 256, 0, stream>>>(t0, W3, b3, t1);

    // Layer 4: t1[N,64] -> recon = (Ahat h) W4 + b4 in d_out [N,2048]
    agg_self_k<64><<<(NN * 16 + 255) / 256, 256, 0, stream>>>(t1, deg, t0);
    edge_scatter_k<64><<<(EE * 16 + 255) / 256, 256, 0, stream>>>(src, dst, nrm, t1, t0);
    gemm_big_k<<<dim3(808, 32), 256, 0, stream>>>(t0, W4, b4, out);
}

// Round 2
// 358.501 us; speedup vs baseline: 1.9055x; 1.9055x over previous
//
#include <hip/hip_runtime.h>

#define NN 51681
#define EE 2048
#define Z_OFF (51681LL * 2048LL)

typedef __bf16 bf16x8 __attribute__((ext_vector_type(8)));
typedef float floatx4 __attribute__((ext_vector_type(4)));

__device__ inline unsigned short f2bf(float x) {
    unsigned u = __float_as_uint(x);
    unsigned r = (u + 0x7FFFu + ((u >> 16) & 1u)) >> 16;
    return (unsigned short)r;
}
__device__ inline float bf2f(unsigned short h) {
    return __uint_as_float(((unsigned)h) << 16);
}

// ---------------- degree / norm prep ----------------

__global__ void deg_init_k(float* __restrict__ deg) {
    int i = blockIdx.x * 256 + threadIdx.x;
    if (i < NN) deg[i] = 1.0f;   // self-loop weight
}

__global__ void deg_scatter_k(const int* __restrict__ dst, const float* __restrict__ w,
                              float* __restrict__ deg) {
    int e = blockIdx.x * 256 + threadIdx.x;
    if (e < EE) atomicAdd(&deg[dst[e]], w[e]);
}

__global__ void norm_edge_k(const int* __restrict__ src, const int* __restrict__ dst,
                            const float* __restrict__ w, const float* __restrict__ deg,
                            float* __restrict__ nrm) {
    int e = blockIdx.x * 256 + threadIdx.x;
    if (e < EE) nrm[e] = rsqrtf(deg[src[e]]) * w[e] * rsqrtf(deg[dst[e]]);
}

// ---------------- aggregation: A = Ahat * X ----------------

template<int FIN>
__global__ void agg_self_k(const float* __restrict__ X, const float* __restrict__ deg,
                           float* __restrict__ A) {
    constexpr int F4 = FIN / 4;
    int tid = blockIdx.x * 256 + threadIdx.x;
    if (tid >= NN * F4) return;
    int j = tid / F4;
    float s = 1.0f / deg[j];
    float4 v = reinterpret_cast<const float4*>(X)[tid];
    reinterpret_cast<float4*>(A)[tid] = make_float4(v.x * s, v.y * s, v.z * s, v.w * s);
}

template<int FIN>
__global__ void edge_scatter_k(const int* __restrict__ src, const int* __restrict__ dst,
                               const float* __restrict__ nrm, const float* __restrict__ X,
                               float* __restrict__ A) {
    constexpr int F4 = FIN / 4;
    int tid = blockIdx.x * 256 + threadIdx.x;
    if (tid >= EE * F4) return;
    int e = tid / F4;
    int f = (tid - e * F4) * 4;
    float n = nrm[e];
    const float4 v = *reinterpret_cast<const float4*>(&X[(long long)src[e] * FIN + f]);
    float* a = &A[(long long)dst[e] * FIN + f];
    atomicAdd(a + 0, n * v.x);
    atomicAdd(a + 1, n * v.y);
    atomicAdd(a + 2, n * v.z);
    atomicAdd(a + 3, n * v.w);
}

// ---------------- small GEMM: out[N,FOUT] = act(A[N,K] @ W[K,FOUT] + b) ----------------

template<int K, int FOUT, bool RELU>
__global__ __launch_bounds__(256) void gemm_small_k(
    const float* __restrict__ A, const float* __restrict__ W,
    const float* __restrict__ bias, float* __restrict__ out) {
    constexpr int NPB = 256 / FOUT;     // nodes per block
    __shared__ float Ws[K * FOUT];
    __shared__ float As[NPB][K];
    __shared__ float bs[FOUT];
    int tid = threadIdx.x;
    for (int i = tid; i < K * FOUT / 4; i += 256)
        reinterpret_cast<float4*>(Ws)[i] = reinterpret_cast<const float4*>(W)[i];
    if (tid < FOUT) bs[tid] = bias[tid];
    int node0 = blockIdx.x * NPB;
    for (int i = tid; i < NPB * (K / 4); i += 256) {
        int r = i / (K / 4);
        int kk = (i - r * (K / 4)) * 4;
        int g = node0 + r;
        float4 v = make_float4(0.f, 0.f, 0.f, 0.f);
        if (g < NN) v = *reinterpret_cast<const float4*>(&A[(long long)g * K + kk]);
        *reinterpret_cast<float4*>(&As[r][kk]) = v;
    }
    __syncthreads();
    int ln = tid / FOUT;
    int n  = tid - ln * FOUT;
    int g = node0 + ln;
    if (g >= NN) return;
    float s = bs[n];
    #pragma unroll
    for (int k = 0; k < K; ++k)
        s = fmaf(As[ln][k], Ws[k * FOUT + n], s);
    if (RELU) s = fmaxf(s, 0.f);
    out[(long long)g * FOUT + n] = s;
}

// ---------------- split-bf16 conversion ----------------

// t0 [NN*64] fp32 -> ahi, alo bf16 (stored as ushort)
__global__ void convert_a_k(const float* __restrict__ t0,
                            ushort* __restrict__ ahi, ushort* __restrict__ alo) {
    int i = blockIdx.x * 256 + threadIdx.x;     // one float4 per thread
    if (i >= NN * 16) return;
    float4 v = reinterpret_cast<const float4*>(t0)[i];
    ushort4 h, l;
    h.x = f2bf(v.x); l.x = f2bf(v.x - bf2f(h.x));
    h.y = f2bf(v.y); l.y = f2bf(v.y - bf2f(h.y));
    h.z = f2bf(v.z); l.z = f2bf(v.z - bf2f(h.z));
    h.w = f2bf(v.w); l.w = f2bf(v.w - bf2f(h.w));
    reinterpret_cast<ushort4*>(ahi)[i] = h;
    reinterpret_cast<ushort4*>(alo)[i] = l;
}

// W4 [64][2048] fp32 -> wthi, wtlo [2048][64] bf16 (transposed)
__global__ void convert_wt_k(const float* __restrict__ W4,
                             ushort* __restrict__ wthi, ushort* __restrict__ wtlo) {
    int i = blockIdx.x * 256 + threadIdx.x;
    if (i >= 64 * 2048) return;
    int k = i >> 11;
    int c = i & 2047;
    float x = W4[i];
    ushort h = f2bf(x);
    ushort l = f2bf(x - bf2f(h));
    wthi[c * 64 + k] = h;
    wtlo[c * 64 + k] = l;
}

// ---------------- big GEMM via split-bf16 MFMA ----------------
// out[N,2048] = A[N,64] @ W[64,2048] + b,  A = ahi+alo, W = wthi+wtlo (transposed [col][k])
// block 256 thr = 4 waves; tile 64 rows x 64 cols; wave = 16 rows x 64 cols.
// No LDS: A frags from global (L3-resident), B frags from global (W 512KB, L2-resident).

__global__ __launch_bounds__(256) void gemm_mfma_k(
    const ushort* __restrict__ ahi, const ushort* __restrict__ alo,
    const ushort* __restrict__ wthi, const ushort* __restrict__ wtlo,
    const float* __restrict__ bias, float* __restrict__ out) {
    int col0 = blockIdx.x * 64;
    int row0 = blockIdx.y * 64;
    int lane = threadIdx.x & 63;
    int wv   = threadIdx.x >> 6;
    int rl   = lane & 15;      // A-row / B-col / D-col within 16
    int kg   = lane >> 4;      // k-group 0..3

    // A fragments: row r, k in [kg*8, kg*8+8) + 32*f  (k-permutation self-consistent w/ B)
    bf16x8 a_hi[2], a_lo[2];
    int r = row0 + wv * 16 + rl;
    if (r < NN) {
        const ushort* p = ahi + (long long)r * 64 + kg * 8;
        const ushort* q = alo + (long long)r * 64 + kg * 8;
        a_hi[0] = *reinterpret_cast<const bf16x8*>(p);
        a_hi[1] = *reinterpret_cast<const bf16x8*>(p + 32);
        a_lo[0] = *reinterpret_cast<const bf16x8*>(q);
        a_lo[1] = *reinterpret_cast<const bf16x8*>(q + 32);
    } else {
        #pragma unroll
        for (int f = 0; f < 2; ++f) {
            #pragma unroll
            for (int i = 0; i < 8; ++i) { a_hi[f][i] = (__bf16)0.0f; a_lo[f][i] = (__bf16)0.0f; }
        }
    }

    // B fragments + bias-initialized accumulators
    bf16x8 b_hi[4][2], b_lo[4][2];
    floatx4 acc[4];
    #pragma unroll
    for (int ct = 0; ct < 4; ++ct) {
        int col = col0 + ct * 16 + rl;
        const ushort* p = wthi + (long long)col * 64 + kg * 8;
        const ushort* q = wtlo + (long long)col * 64 + kg * 8;
        b_hi[ct][0] = *reinterpret_cast<const bf16x8*>(p);
        b_hi[ct][1] = *reinterpret_cast<const bf16x8*>(p + 32);
        b_lo[ct][0] = *reinterpret_cast<const bf16x8*>(q);
        b_lo[ct][1] = *reinterpret_cast<const bf16x8*>(q + 32);
        float bv = bias[col];
        acc[ct][0] = bv; acc[ct][1] = bv; acc[ct][2] = bv; acc[ct][3] = bv;
    }

    // 3-product split: hi*hi + hi*lo + lo*hi  (lo*lo ~ 2^-18, dropped)
    #pragma unroll
    for (int ct = 0; ct < 4; ++ct) {
        #pragma unroll
        for (int f = 0; f < 2; ++f) {
            acc[ct] = __builtin_amdgcn_mfma_f32_16x16x32_bf16(a_hi[f], b_hi[ct][f], acc[ct], 0, 0, 0);
            acc[ct] = __builtin_amdgcn_mfma_f32_16x16x32_bf16(a_hi[f], b_lo[ct][f], acc[ct], 0, 0, 0);
            acc[ct] = __builtin_amdgcn_mfma_f32_16x16x32_bf16(a_lo[f], b_hi[ct][f], acc[ct], 0, 0, 0);
        }
    }

    // store: D col = lane&15, row = (lane>>4)*4 + reg   [m89-verified]
    int orow = row0 + wv * 16 + kg * 4;
    #pragma unroll
    for (int ct = 0; ct < 4; ++ct) {
        int col = col0 + ct * 16 + rl;
        #pragma unroll
        for (int i = 0; i < 4; ++i) {
            int rr = orow + i;
            if (rr < NN) out[(long long)rr * 2048 + col] = acc[ct][i];
        }
    }
}

// ---------------- launch ----------------

extern "C" void kernel_launch(void* const* d_in, const int* in_sizes, int n_in,
                              void* d_out, int out_size, void* d_ws, size_t ws_size,
                              hipStream_t stream) {
    const int*   edge_index = (const int*)d_in[0];   // [2, EE]
    const int*   src = edge_index;
    const int*   dst = edge_index + EE;
    const float* ew  = (const float*)d_in[1];
    const float* emb = (const float*)d_in[2];        // [NN,32]
    const float* W1  = (const float*)d_in[3];        // [32,64]
    const float* b1  = (const float*)d_in[4];
    const float* W2  = (const float*)d_in[5];        // [64,32]
    const float* b2  = (const float*)d_in[6];
    const float* W3  = (const float*)d_in[7];        // [32,64]
    const float* b3  = (const float*)d_in[8];
    const float* W4  = (const float*)d_in[9];        // [64,2048]
    const float* b4  = (const float*)d_in[10];

    float* out = (float*)d_out;                      // recon_x [NN,2048]
    float* z   = out + Z_OFF;                        // z [NN,32]

    float* ws  = (float*)d_ws;
    float* deg = ws;                                 // NN floats
    float* nrm = ws + 51684;                         // EE floats
    float* t0  = ws + 53732;                         // NN*64 (agg buffer)
    float* t1  = t0 + 3307584;                       // NN*64 (layer output)

    // normalization (shared by all 4 layers)
    deg_init_k<<<(NN + 255) / 256, 256, 0, stream>>>(deg);
    deg_scatter_k<<<(EE + 255) / 256, 256, 0, stream>>>(dst, ew, deg);
    norm_edge_k<<<(EE + 255) / 256, 256, 0, stream>>>(src, dst, ew, deg, nrm);

    // Layer 1: emb[N,32] -> x1 = relu((Ahat emb) W1 + b1) in t1[N,64]
    agg_self_k<32><<<(NN * 8 + 255) / 256, 256, 0, stream>>>(emb, deg, t0);
    edge_scatter_k<32><<<(EE * 8 + 255) / 256, 256, 0, stream>>>(src, dst, nrm, emb, t0);
    gemm_small_k<32, 64, true><<<(NN + 3) / 4, 256, 0, stream>>>(t0, W1, b1, t1);

    // Layer 2: t1[N,64] -> z = relu((Ahat x1) W2 + b2) in d_out z-region [N,32]
    agg_self_k<64><<<(NN * 16 + 255) / 256, 256, 0, stream>>>(t1, deg, t0);
    edge_scatter_k<64><<<(EE * 16 + 255) / 256, 256, 0, stream>>>(src, dst, nrm, t1, t0);
    gemm_small_k<64, 32, true><<<(NN + 7) / 8, 256, 0, stream>>>(t0, W2, b2, z);

    // Layer 3: z[N,32] -> h = relu((Ahat z) W3 + b3) in t1[N,64]
    agg_self_k<32><<<(NN * 8 + 255) / 256, 256, 0, stream>>>(z, deg, t0);
    edge_scatter_k<32><<<(EE * 8 + 255) / 256, 256, 0, stream>>>(src, dst, nrm, z, t0);
    gemm_small_k<32, 64, true><<<(NN + 3) / 4, 256, 0, stream>>>(t0, W3, b3, t1);

    // Layer 4: agg h -> t0; split-bf16 convert; MFMA GEMM
    agg_self_k<64><<<(NN * 16 + 255) / 256, 256, 0, stream>>>(t1, deg, t0);
    edge_scatter_k<64><<<(EE * 16 + 255) / 256, 256, 0, stream>>>(src, dst, nrm, t1, t0);

    // converts reuse dead regions: ahi/alo overwrite t1 (h dead after agg);
    // wthi/wtlo overwrite t0 AFTER convert_a_k consumed it (stream-serial).
    ushort* ahi  = (ushort*)t1;
    ushort* alo  = ahi + (size_t)NN * 64;
    ushort* wthi = (ushort*)t0;
    ushort* wtlo = wthi + 2048 * 64;
    convert_a_k<<<(NN * 16 + 255) / 256, 256, 0, stream>>>(t0, ahi, alo);
    convert_wt_k<<<(64 * 2048 + 255) / 256, 256, 0, stream>>>(W4, wthi, wtlo);

    gemm_mfma_k<<<dim3(32, 808), 256, 0, stream>>>(ahi, alo, wthi, wtlo, b4, out);
}

// Round 3
// 341.495 us; speedup vs baseline: 2.0004x; 1.0498x over previous
//
#include <hip/hip_runtime.h>

#define NN 51681
#define EE 2048
#define Z_OFF (51681LL * 2048LL)

typedef __bf16 bf16x8 __attribute__((ext_vector_type(8)));
typedef unsigned short ushort8 __attribute__((ext_vector_type(8)));
typedef float floatx4 __attribute__((ext_vector_type(4)));

__device__ inline unsigned short f2bf(float x) {
    unsigned u = __float_as_uint(x);
    unsigned r = (u + 0x7FFFu + ((u >> 16) & 1u)) >> 16;
    return (unsigned short)r;
}
__device__ inline float bf2f(unsigned short h) {
    return __uint_as_float(((unsigned)h) << 16);
}

// ---------------- utility: zero a float buffer ----------------

__global__ void zero_k(float4* __restrict__ p, int n4) {
    int i = blockIdx.x * 256 + threadIdx.x;
    if (i < n4) p[i] = make_float4(0.f, 0.f, 0.f, 0.f);
}

// ---------------- degree / norm prep ----------------

__global__ void deg_init_k(float* __restrict__ deg) {
    int i = blockIdx.x * 256 + threadIdx.x;
    if (i < NN) deg[i] = 1.0f;   // self-loop weight
}

__global__ void deg_scatter_k(const int* __restrict__ dst, const float* __restrict__ w,
                              float* __restrict__ deg) {
    int e = blockIdx.x * 256 + threadIdx.x;
    if (e < EE) atomicAdd(&deg[dst[e]], w[e]);
}

__global__ void norm_edge_k(const int* __restrict__ src, const int* __restrict__ dst,
                            const float* __restrict__ w, const float* __restrict__ deg,
                            float* __restrict__ nrm) {
    int e = blockIdx.x * 256 + threadIdx.x;
    if (e < EE) nrm[e] = rsqrtf(deg[src[e]]) * w[e] * rsqrtf(deg[dst[e]]);
}

// ---------------- edge scatter: E[dst] += norm * X[src]  (E pre-zeroed) ----------------

template<int FIN>
__global__ void edge_scatter_k(const int* __restrict__ src, const int* __restrict__ dst,
                               const float* __restrict__ nrm, const float* __restrict__ X,
                               float* __restrict__ E) {
    constexpr int F4 = FIN / 4;
    int tid = blockIdx.x * 256 + threadIdx.x;
    if (tid >= EE * F4) return;
    int e = tid / F4;
    int f = (tid - e * F4) * 4;
    float n = nrm[e];
    const float4 v = *reinterpret_cast<const float4*>(&X[(long long)src[e] * FIN + f]);
    float* a = &E[(long long)dst[e] * FIN + f];
    atomicAdd(a + 0, n * v.x);
    atomicAdd(a + 1, n * v.y);
    atomicAdd(a + 2, n * v.z);
    atomicAdd(a + 3, n * v.w);
}

// ---------- fused small GEMM: out = act((E + X/deg) @ W + b) ----------

template<int K, int FOUT, bool RELU>
__global__ __launch_bounds__(256) void gemm_small_k(
    const float* __restrict__ E, const float* __restrict__ X,
    const float* __restrict__ deg, const float* __restrict__ W,
    const float* __restrict__ bias, float* __restrict__ out) {
    constexpr int NPB = 256 / FOUT;     // nodes per block
    __shared__ float Ws[K * FOUT];
    __shared__ float As[NPB][K];
    __shared__ float bs[FOUT];
    int tid = threadIdx.x;
    for (int i = tid; i < K * FOUT / 4; i += 256)
        reinterpret_cast<float4*>(Ws)[i] = reinterpret_cast<const float4*>(W)[i];
    if (tid < FOUT) bs[tid] = bias[tid];
    int node0 = blockIdx.x * NPB;
    for (int i = tid; i < NPB * (K / 4); i += 256) {
        int r = i / (K / 4);
        int kk = (i - r * (K / 4)) * 4;
        int g = node0 + r;
        float4 v = make_float4(0.f, 0.f, 0.f, 0.f);
        if (g < NN) {
            float s = 1.0f / deg[g];
            float4 ev = *reinterpret_cast<const float4*>(&E[(long long)g * K + kk]);
            float4 xv = *reinterpret_cast<const float4*>(&X[(long long)g * K + kk]);
            v = make_float4(ev.x + xv.x * s, ev.y + xv.y * s,
                            ev.z + xv.z * s, ev.w + xv.w * s);
        }
        *reinterpret_cast<float4*>(&As[r][kk]) = v;
    }
    __syncthreads();
    int ln = tid / FOUT;
    int n  = tid - ln * FOUT;
    int g = node0 + ln;
    if (g >= NN) return;
    float s = bs[n];
    #pragma unroll
    for (int k = 0; k < K; ++k)
        s = fmaf(As[ln][k], Ws[k * FOUT + n], s);
    if (RELU) s = fmaxf(s, 0.f);
    out[(long long)g * FOUT + n] = s;
}

// ---------------- W4 [64][2048] fp32 -> wthi, wtlo [2048][64] bf16 ----------------

__global__ void convert_wt_k(const float* __restrict__ W4,
                             ushort* __restrict__ wthi, ushort* __restrict__ wtlo) {
    int i = blockIdx.x * 256 + threadIdx.x;
    if (i >= 64 * 2048) return;
    int k = i >> 11;
    int c = i & 2047;
    float x = W4[i];
    ushort h = f2bf(x);
    ushort l = f2bf(x - bf2f(h));
    wthi[c * 64 + k] = h;
    wtlo[c * 64 + k] = l;
}

// ---------------- big GEMM: out[N,2048] = (E + H/deg)[N,64] @ W[64,2048] + b ----------
// Swapped MFMA operands: A-slot = W^T fragment (m = out-col), B-slot = node fragment
// (n = node row).  D: col(lane&15)=node, row(reg)=out-col  ->  contiguous float4 store.
// Block = 4 waves, 64 nodes x 512 cols (32 col-tiles).  A-side hi/lo split in-register.

__global__ __launch_bounds__(256) void gemm_big_k(
    const float* __restrict__ E, const float* __restrict__ H,
    const float* __restrict__ deg,
    const ushort* __restrict__ wthi, const ushort* __restrict__ wtlo,
    const float* __restrict__ bias, float* __restrict__ out) {
    int lane = threadIdx.x & 63;
    int wv   = threadIdx.x >> 6;
    int rl   = lane & 15;
    int kg   = lane >> 4;
    int node = blockIdx.y * 64 + wv * 16 + rl;
    bool valid = node < NN;

    // ---- prologue: build node fragments (hi/lo split in-register) ----
    bf16x8 nb_hi[2], nb_lo[2];
    {
        float v[2][8];
        if (valid) {
            float s = 1.0f / deg[node];
            const float* e0 = E + (long long)node * 64 + kg * 8;
            const float* h0 = H + (long long)node * 64 + kg * 8;
            #pragma unroll
            for (int f = 0; f < 2; ++f) {
                float4 ea = *reinterpret_cast<const float4*>(e0 + f * 32);
                float4 eb = *reinterpret_cast<const float4*>(e0 + f * 32 + 4);
                float4 ha = *reinterpret_cast<const float4*>(h0 + f * 32);
                float4 hb = *reinterpret_cast<const float4*>(h0 + f * 32 + 4);
                v[f][0] = ea.x + ha.x * s; v[f][1] = ea.y + ha.y * s;
                v[f][2] = ea.z + ha.z * s; v[f][3] = ea.w + ha.w * s;
                v[f][4] = eb.x + hb.x * s; v[f][5] = eb.y + hb.y * s;
                v[f][6] = eb.z + hb.z * s; v[f][7] = eb.w + hb.w * s;
            }
        } else {
            #pragma unroll
            for (int f = 0; f < 2; ++f)
                #pragma unroll
                for (int i = 0; i < 8; ++i) v[f][i] = 0.f;
        }
        #pragma unroll
        for (int f = 0; f < 2; ++f) {
            ushort8 h8, l8;
            #pragma unroll
            for (int i = 0; i < 8; ++i) {
                unsigned u = __float_as_uint(v[f][i]) & 0xFFFF0000u;  // hi = truncate
                h8[i] = (unsigned short)(u >> 16);
                l8[i] = f2bf(v[f][i] - __uint_as_float(u));
            }
            nb_hi[f] = __builtin_bit_cast(bf16x8, h8);
            nb_lo[f] = __builtin_bit_cast(bf16x8, l8);
        }
    }

    // ---- col-tile loop: 32 tiles of 16 cols ----
    int cbase = blockIdx.x * 512;
    #pragma unroll 4
    for (int t = 0; t < 32; ++t) {
        int cb = cbase + t * 16;
        int wc = cb + rl;
        const ushort* ph = wthi + wc * 64 + kg * 8;
        const ushort* pl = wtlo + wc * 64 + kg * 8;
        bf16x8 wa_hi0 = *reinterpret_cast<const bf16x8*>(ph);
        bf16x8 wa_hi1 = *reinterpret_cast<const bf16x8*>(ph + 32);
        bf16x8 wa_lo0 = *reinterpret_cast<const bf16x8*>(pl);
        bf16x8 wa_lo1 = *reinterpret_cast<const bf16x8*>(pl + 32);

        floatx4 acc = *reinterpret_cast<const floatx4*>(&bias[cb + kg * 4]);
        acc = __builtin_amdgcn_mfma_f32_16x16x32_bf16(wa_hi0, nb_hi[0], acc, 0, 0, 0);
        acc = __builtin_amdgcn_mfma_f32_16x16x32_bf16(wa_hi0, nb_lo[0], acc, 0, 0, 0);
        acc = __builtin_amdgcn_mfma_f32_16x16x32_bf16(wa_lo0, nb_hi[0], acc, 0, 0, 0);
        acc = __builtin_amdgcn_mfma_f32_16x16x32_bf16(wa_hi1, nb_hi[1], acc, 0, 0, 0);
        acc = __builtin_amdgcn_mfma_f32_16x16x32_bf16(wa_hi1, nb_lo[1], acc, 0, 0, 0);
        acc = __builtin_amdgcn_mfma_f32_16x16x32_bf16(wa_lo1, nb_hi[1], acc, 0, 0, 0);

        if (valid)
            *reinterpret_cast<floatx4*>(&out[(long long)node * 2048 + cb + kg * 4]) = acc;
    }
}

// ---------------- launch ----------------

extern "C" void kernel_launch(void* const* d_in, const int* in_sizes, int n_in,
                              void* d_out, int out_size, void* d_ws, size_t ws_size,
                              hipStream_t stream) {
    const int*   edge_index = (const int*)d_in[0];   // [2, EE]
    const int*   src = edge_index;
    const int*   dst = edge_index + EE;
    const float* ew  = (const float*)d_in[1];
    const float* emb = (const float*)d_in[2];        // [NN,32]
    const float* W1  = (const float*)d_in[3];        // [32,64]
    const float* b1  = (const float*)d_in[4];
    const float* W2  = (const float*)d_in[5];        // [64,32]
    const float* b2  = (const float*)d_in[6];
    const float* W3  = (const float*)d_in[7];        // [32,64]
    const float* b3  = (const float*)d_in[8];
    const float* W4  = (const float*)d_in[9];        // [64,2048]
    const float* b4  = (const float*)d_in[10];

    float* out = (float*)d_out;                      // recon_x [NN,2048]
    float* z   = out + Z_OFF;                        // z [NN,32]

    float* ws   = (float*)d_ws;
    float* deg  = ws;                                // NN floats (pad 51684)
    float* nrm  = ws + 51684;                        // EE floats
    float* Ebuf = ws + 53732;                        // NN*64 floats (edge accum)
    float* t1   = Ebuf + 3307584;                    // NN*64 floats (layer output)
    ushort* wthi = (ushort*)(t1 + 3307584);          // 2048*64 ushorts
    ushort* wtlo = wthi + 2048 * 64;

    // normalization (shared by all 4 layers)
    deg_init_k<<<(NN + 255) / 256, 256, 0, stream>>>(deg);
    deg_scatter_k<<<(EE + 255) / 256, 256, 0, stream>>>(dst, ew, deg);
    norm_edge_k<<<(EE + 255) / 256, 256, 0, stream>>>(src, dst, ew, deg, nrm);

    // Layer 1: x1 = relu((E + emb/deg) @ W1 + b1) in t1[N,64],  E = edges(emb)
    zero_k<<<(NN * 8 + 255) / 256, 256, 0, stream>>>((float4*)Ebuf, NN * 8);
    edge_scatter_k<32><<<(EE * 8 + 255) / 256, 256, 0, stream>>>(src, dst, nrm, emb, Ebuf);
    gemm_small_k<32, 64, true><<<(NN + 3) / 4, 256, 0, stream>>>(Ebuf, emb, deg, W1, b1, t1);

    // Layer 2: z = relu((E + x1/deg) @ W2 + b2) in d_out z-region [N,32]
    zero_k<<<(NN * 16 + 255) / 256, 256, 0, stream>>>((float4*)Ebuf, NN * 16);
    edge_scatter_k<64><<<(EE * 16 + 255) / 256, 256, 0, stream>>>(src, dst, nrm, t1, Ebuf);
    gemm_small_k<64, 32, true><<<(NN + 7) / 8, 256, 0, stream>>>(Ebuf, t1, deg, W2, b2, z);

    // Layer 3: h = relu((E + z/deg) @ W3 + b3) in t1[N,64]
    zero_k<<<(NN * 8 + 255) / 256, 256, 0, stream>>>((float4*)Ebuf, NN * 8);
    edge_scatter_k<32><<<(EE * 8 + 255) / 256, 256, 0, stream>>>(src, dst, nrm, z, Ebuf);
    gemm_small_k<32, 64, true><<<(NN + 3) / 4, 256, 0, stream>>>(Ebuf, z, deg, W3, b3, t1);

    // Layer 4: recon = (E + h/deg) @ W4 + b4 in d_out [N,2048]
    zero_k<<<(NN * 16 + 255) / 256, 256, 0, stream>>>((float4*)Ebuf, NN * 16);
    edge_scatter_k<64><<<(EE * 16 + 255) / 256, 256, 0, stream>>>(src, dst, nrm, t1, Ebuf);
    convert_wt_k<<<(64 * 2048 + 255) / 256, 256, 0, stream>>>(W4, wthi, wtlo);
    gemm_big_k<<<dim3(4, 808), 256, 0, stream>>>(Ebuf, t1, deg, wthi, wtlo, b4, out);
}

// Round 4
// 320.008 us; speedup vs baseline: 2.1347x; 1.0671x over previous
//
#include <hip/hip_runtime.h>

#define NN 51681
#define EE 2048
#define Z_OFF (51681LL * 2048LL)

typedef __bf16 bf16x8 __attribute__((ext_vector_type(8)));
typedef unsigned short ushort8 __attribute__((ext_vector_type(8)));
typedef float floatx4 __attribute__((ext_vector_type(4)));

__device__ inline unsigned short f2bf(float x) {
    unsigned u = __float_as_uint(x);
    unsigned r = (u + 0x7FFFu + ((u >> 16) & 1u)) >> 16;
    return (unsigned short)r;
}
__device__ inline float bf2f(unsigned short h) {
    return __uint_as_float(((unsigned)h) << 16);
}
__device__ inline void nt_store4(float* p, floatx4 v) {
    __builtin_nontemporal_store(v, reinterpret_cast<floatx4*>(p));
}

// ---------------- utility: zero a float buffer ----------------

__global__ void zero_k(float4* __restrict__ p, int n4) {
    int i = blockIdx.x * 256 + threadIdx.x;
    if (i < n4) p[i] = make_float4(0.f, 0.f, 0.f, 0.f);
}

// ---------------- degree / norm prep ----------------

__global__ void deg_init_k(float* __restrict__ deg) {
    int i = blockIdx.x * 256 + threadIdx.x;
    if (i < NN) deg[i] = 1.0f;   // self-loop weight
}

__global__ void deg_scatter_k(const int* __restrict__ dst, const float* __restrict__ w,
                              float* __restrict__ deg) {
    int e = blockIdx.x * 256 + threadIdx.x;
    if (e < EE) atomicAdd(&deg[dst[e]], w[e]);
}

__global__ void norm_edge_k(const int* __restrict__ src, const int* __restrict__ dst,
                            const float* __restrict__ w, const float* __restrict__ deg,
                            float* __restrict__ nrm) {
    int e = blockIdx.x * 256 + threadIdx.x;
    if (e < EE) nrm[e] = rsqrtf(deg[src[e]]) * w[e] * rsqrtf(deg[dst[e]]);
}

// ---------------- edge scatter: E[dst] += norm * X[src]  (E pre-zeroed) ----------------

template<int FIN>
__global__ void edge_scatter_k(const int* __restrict__ src, const int* __restrict__ dst,
                               const float* __restrict__ nrm, const float* __restrict__ X,
                               float* __restrict__ E) {
    constexpr int F4 = FIN / 4;
    int tid = blockIdx.x * 256 + threadIdx.x;
    if (tid >= EE * F4) return;
    int e = tid / F4;
    int f = (tid - e * F4) * 4;
    float n = nrm[e];
    const float4 v = *reinterpret_cast<const float4*>(&X[(long long)src[e] * FIN + f]);
    float* a = &E[(long long)dst[e] * FIN + f];
    atomicAdd(a + 0, n * v.x);
    atomicAdd(a + 1, n * v.y);
    atomicAdd(a + 2, n * v.z);
    atomicAdd(a + 3, n * v.w);
}

// ---------- fused small GEMM: out = act((E + X/deg) @ W + b) ----------

template<int K, int FOUT, bool RELU>
__global__ __launch_bounds__(256) void gemm_small_k(
    const float* __restrict__ E, const float* __restrict__ X,
    const float* __restrict__ deg, const float* __restrict__ W,
    const float* __restrict__ bias, float* __restrict__ out) {
    constexpr int NPB = 256 / FOUT;     // nodes per block
    __shared__ float Ws[K * FOUT];
    __shared__ float As[NPB][K];
    __shared__ float bs[FOUT];
    int tid = threadIdx.x;
    for (int i = tid; i < K * FOUT / 4; i += 256)
        reinterpret_cast<float4*>(Ws)[i] = reinterpret_cast<const float4*>(W)[i];
    if (tid < FOUT) bs[tid] = bias[tid];
    int node0 = blockIdx.x * NPB;
    for (int i = tid; i < NPB * (K / 4); i += 256) {
        int r = i / (K / 4);
        int kk = (i - r * (K / 4)) * 4;
        int g = node0 + r;
        float4 v = make_float4(0.f, 0.f, 0.f, 0.f);
        if (g < NN) {
            float s = 1.0f / deg[g];
            float4 ev = *reinterpret_cast<const float4*>(&E[(long long)g * K + kk]);
            float4 xv = *reinterpret_cast<const float4*>(&X[(long long)g * K + kk]);
            v = make_float4(ev.x + xv.x * s, ev.y + xv.y * s,
                            ev.z + xv.z * s, ev.w + xv.w * s);
        }
        *reinterpret_cast<float4*>(&As[r][kk]) = v;
    }
    __syncthreads();
    int ln = tid / FOUT;
    int n  = tid - ln * FOUT;
    int g = node0 + ln;
    if (g >= NN) return;
    float s = bs[n];
    #pragma unroll
    for (int k = 0; k < K; ++k)
        s = fmaf(As[ln][k], Ws[k * FOUT + n], s);
    if (RELU) s = fmaxf(s, 0.f);
    out[(long long)g * FOUT + n] = s;
}

// ---------------- W4 [64][2048] fp32 -> wthi, wtlo [2048][64] bf16 ----------------

__global__ void convert_wt_k(const float* __restrict__ W4,
                             ushort* __restrict__ wthi, ushort* __restrict__ wtlo) {
    int i = blockIdx.x * 256 + threadIdx.x;
    if (i >= 64 * 2048) return;
    int k = i >> 11;
    int c = i & 2047;
    float x = W4[i];
    ushort h = f2bf(x);
    ushort l = f2bf(x - bf2f(h));
    wthi[c * 64 + k] = h;
    wtlo[c * 64 + k] = l;
}

// ---------------- big GEMM: out[N,2048] = (E + H/deg)[N,64] @ W[64,2048] + b ----------
// Swapped MFMA operands (A-slot = W^T, B-slot = node) -> D: col(lane&15)=node,
// row(reg)=out-col.  Epilogue: wave-private LDS staging (16 nodes x 128 cols,
// XOR-swizzled) flushed as coalesced 512B-per-row wave stores (nontemporal).

__global__ __launch_bounds__(256) void gemm_big_k(
    const float* __restrict__ E, const float* __restrict__ H,
    const float* __restrict__ deg,
    const ushort* __restrict__ wthi, const ushort* __restrict__ wtlo,
    const float* __restrict__ bias, float* __restrict__ out) {
    __shared__ float lds[4][16][128];   // 32 KB, wave-private patches
    int lane = threadIdx.x & 63;
    int wv   = threadIdx.x >> 6;
    int rl   = lane & 15;
    int kg   = lane >> 4;
    int node = blockIdx.y * 64 + wv * 16 + rl;
    bool valid = node < NN;

    // ---- prologue: build node fragments (hi/lo split in-register) ----
    bf16x8 nb_hi[2], nb_lo[2];
    {
        float v[2][8];
        if (valid) {
            float s = 1.0f / deg[node];
            const float* e0 = E + (long long)node * 64 + kg * 8;
            const float* h0 = H + (long long)node * 64 + kg * 8;
            #pragma unroll
            for (int f = 0; f < 2; ++f) {
                float4 ea = *reinterpret_cast<const float4*>(e0 + f * 32);
                float4 eb = *reinterpret_cast<const float4*>(e0 + f * 32 + 4);
                float4 ha = *reinterpret_cast<const float4*>(h0 + f * 32);
                float4 hb = *reinterpret_cast<const float4*>(h0 + f * 32 + 4);
                v[f][0] = ea.x + ha.x * s; v[f][1] = ea.y + ha.y * s;
                v[f][2] = ea.z + ha.z * s; v[f][3] = ea.w + ha.w * s;
                v[f][4] = eb.x + hb.x * s; v[f][5] = eb.y + hb.y * s;
                v[f][6] = eb.z + hb.z * s; v[f][7] = eb.w + hb.w * s;
            }
        } else {
            #pragma unroll
            for (int f = 0; f < 2; ++f)
                #pragma unroll
                for (int i = 0; i < 8; ++i) v[f][i] = 0.f;
        }
        #pragma unroll
        for (int f = 0; f < 2; ++f) {
            ushort8 h8, l8;
            #pragma unroll
            for (int i = 0; i < 8; ++i) {
                unsigned u = __float_as_uint(v[f][i]) & 0xFFFF0000u;  // hi = truncate
                h8[i] = (unsigned short)(u >> 16);
                l8[i] = f2bf(v[f][i] - __uint_as_float(u));
            }
            nb_hi[f] = __builtin_bit_cast(bf16x8, h8);
            nb_lo[f] = __builtin_bit_cast(bf16x8, l8);
        }
    }

    int cbase = blockIdx.x * 512;
    int grow_base = blockIdx.y * 64 + wv * 16;

    for (int g = 0; g < 4; ++g) {
        // ---- compute 8 col-tiles (128 cols), stage into wave-private LDS ----
        #pragma unroll
        for (int tl = 0; tl < 8; ++tl) {
            int cb = cbase + g * 128 + tl * 16;
            int wc = cb + rl;
            const ushort* ph = wthi + wc * 64 + kg * 8;
            const ushort* pl = wtlo + wc * 64 + kg * 8;
            bf16x8 wa_hi0 = *reinterpret_cast<const bf16x8*>(ph);
            bf16x8 wa_hi1 = *reinterpret_cast<const bf16x8*>(ph + 32);
            bf16x8 wa_lo0 = *reinterpret_cast<const bf16x8*>(pl);
            bf16x8 wa_lo1 = *reinterpret_cast<const bf16x8*>(pl + 32);

            floatx4 acc = *reinterpret_cast<const floatx4*>(&bias[cb + kg * 4]);
            acc = __builtin_amdgcn_mfma_f32_16x16x32_bf16(wa_hi0, nb_hi[0], acc, 0, 0, 0);
            acc = __builtin_amdgcn_mfma_f32_16x16x32_bf16(wa_hi0, nb_lo[0], acc, 0, 0, 0);
            acc = __builtin_amdgcn_mfma_f32_16x16x32_bf16(wa_lo0, nb_hi[0], acc, 0, 0, 0);
            acc = __builtin_amdgcn_mfma_f32_16x16x32_bf16(wa_hi1, nb_hi[1], acc, 0, 0, 0);
            acc = __builtin_amdgcn_mfma_f32_16x16x32_bf16(wa_hi1, nb_lo[1], acc, 0, 0, 0);
            acc = __builtin_amdgcn_mfma_f32_16x16x32_bf16(wa_lo1, nb_hi[1], acc, 0, 0, 0);

            // stage: row rl, float4-col (tl*4+kg), XOR-swizzled for bank spread
            int c4w = (tl * 4 + kg) ^ (rl & 7);
            *reinterpret_cast<floatx4*>(&lds[wv][rl][c4w * 4]) = acc;
        }
        // ---- flush: coalesced 512B-per-row segments, 2 rows per wave-store ----
        // wave-private region + in-order DS pipe: no __syncthreads needed
        int rhalf = lane >> 5;         // 0..1
        int c4r   = lane & 31;         // output float4-col within 128-col group
        #pragma unroll
        for (int rr = 0; rr < 8; ++rr) {
            int r = rr * 2 + rhalf;
            int cc4 = c4r ^ (r & 7);
            floatx4 v = *reinterpret_cast<const floatx4*>(&lds[wv][r][cc4 * 4]);
            int grow = grow_base + r;
            if (grow < NN)
                nt_store4(&out[(long long)grow * 2048 + cbase + g * 128 + c4r * 4], v);
        }
    }
}

// ---------------- launch ----------------

extern "C" void kernel_launch(void* const* d_in, const int* in_sizes, int n_in,
                              void* d_out, int out_size, void* d_ws, size_t ws_size,
                              hipStream_t stream) {
    const int*   edge_index = (const int*)d_in[0];   // [2, EE]
    const int*   src = edge_index;
    const int*   dst = edge_index + EE;
    const float* ew  = (const float*)d_in[1];
    const float* emb = (const float*)d_in[2];        // [NN,32]
    const float* W1  = (const float*)d_in[3];        // [32,64]
    const float* b1  = (const float*)d_in[4];
    const float* W2  = (const float*)d_in[5];        // [64,32]
    const float* b2  = (const float*)d_in[6];
    const float* W3  = (const float*)d_in[7];        // [32,64]
    const float* b3  = (const float*)d_in[8];
    const float* W4  = (const float*)d_in[9];        // [64,2048]
    const float* b4  = (const float*)d_in[10];

    float* out = (float*)d_out;                      // recon_x [NN,2048]
    float* z   = out + Z_OFF;                        // z [NN,32]

    float* ws   = (float*)d_ws;
    float* deg  = ws;                                // NN floats (pad 51684)
    float* nrm  = ws + 51684;                        // EE floats
    float* Ebuf = ws + 53732;                        // NN*64 floats (edge accum)
    float* t1   = Ebuf + 3307584;                    // NN*64 floats (layer output)
    ushort* wthi = (ushort*)(t1 + 3307584);          // 2048*64 ushorts
    ushort* wtlo = wthi + 2048 * 64;

    // normalization (shared by all 4 layers)
    deg_init_k<<<(NN + 255) / 256, 256, 0, stream>>>(deg);
    deg_scatter_k<<<(EE + 255) / 256, 256, 0, stream>>>(dst, ew, deg);
    norm_edge_k<<<(EE + 255) / 256, 256, 0, stream>>>(src, dst, ew, deg, nrm);

    // Layer 1: x1 = relu((E + emb/deg) @ W1 + b1) in t1[N,64],  E = edges(emb)
    zero_k<<<(NN * 8 + 255) / 256, 256, 0, stream>>>((float4*)Ebuf, NN * 8);
    edge_scatter_k<32><<<(EE * 8 + 255) / 256, 256, 0, stream>>>(src, dst, nrm, emb, Ebuf);
    gemm_small_k<32, 64, true><<<(NN + 3) / 4, 256, 0, stream>>>(Ebuf, emb, deg, W1, b1, t1);

    // Layer 2: z = relu((E + x1/deg) @ W2 + b2) in d_out z-region [N,32]
    zero_k<<<(NN * 16 + 255) / 256, 256, 0, stream>>>((float4*)Ebuf, NN * 16);
    edge_scatter_k<64><<<(EE * 16 + 255) / 256, 256, 0, stream>>>(src, dst, nrm, t1, Ebuf);
    gemm_small_k<64, 32, true><<<(NN + 7) / 8, 256, 0, stream>>>(Ebuf, t1, deg, W2, b2, z);

    // Layer 3: h = relu((E + z/deg) @ W3 + b3) in t1[N,64]
    zero_k<<<(NN * 8 + 255) / 256, 256, 0, stream>>>((float4*)Ebuf, NN * 8);
    edge_scatter_k<32><<<(EE * 8 + 255) / 256, 256, 0, stream>>>(src, dst, nrm, z, Ebuf);
    gemm_small_k<32, 64, true><<<(NN + 3) / 4, 256, 0, stream>>>(Ebuf, z, deg, W3, b3, t1);

    // Layer 4: recon = (E + h/deg) @ W4 + b4 in d_out [N,2048]
    zero_k<<<(NN * 16 + 255) / 256, 256, 0, stream>>>((float4*)Ebuf, NN * 16);
    edge_scatter_k<64><<<(EE * 16 + 255) / 256, 256, 0, stream>>>(src, dst, nrm, t1, Ebuf);
    convert_wt_k<<<(64 * 2048 + 255) / 256, 256, 0, stream>>>(W4, wthi, wtlo);
    gemm_big_k<<<dim3(4, 808), 256, 0, stream>>>(Ebuf, t1, deg, wthi, wtlo, b4, out);
}

// Round 5
// 305.029 us; speedup vs baseline: 2.2395x; 1.0491x over previous
//
#include <hip/hip_runtime.h>

#define NN 51681
#define EE 2048
#define Z_OFF (51681LL * 2048LL)

typedef __bf16 bf16x8 __attribute__((ext_vector_type(8)));
typedef unsigned short ushort8 __attribute__((ext_vector_type(8)));
typedef float floatx4 __attribute__((ext_vector_type(4)));

__device__ inline unsigned short f2bf(float x) {
    unsigned u = __float_as_uint(x);
    unsigned r = (u + 0x7FFFu + ((u >> 16) & 1u)) >> 16;
    return (unsigned short)r;
}
__device__ inline float bf2f(unsigned short h) {
    return __uint_as_float(((unsigned)h) << 16);
}
__device__ inline void nt_store4(float* p, floatx4 v) {
    __builtin_nontemporal_store(v, reinterpret_cast<floatx4*>(p));
}

// ---------------- degree / norm prep ----------------

__global__ void deg_init_k(float* __restrict__ deg) {
    int i = blockIdx.x * 256 + threadIdx.x;
    if (i < NN) deg[i] = 1.0f;   // self-loop weight
}

__global__ void deg_scatter_k(const int* __restrict__ dst, const float* __restrict__ w,
                              float* __restrict__ deg) {
    int e = blockIdx.x * 256 + threadIdx.x;
    if (e < EE) atomicAdd(&deg[dst[e]], w[e]);
}

__global__ void norm_edge_k(const int* __restrict__ src, const int* __restrict__ dst,
                            const float* __restrict__ w, const float* __restrict__ deg,
                            float* __restrict__ nrm) {
    int e = blockIdx.x * 256 + threadIdx.x;
    if (e < EE) nrm[e] = rsqrtf(deg[src[e]]) * w[e] * rsqrtf(deg[dst[e]]);
}

// ---------------- zero only the E-rows that edges will touch ----------------

template<int FIN>
__global__ void zero_rows_k(const int* __restrict__ dst, float* __restrict__ E) {
    constexpr int F4 = FIN / 4;
    int tid = blockIdx.x * 256 + threadIdx.x;
    if (tid >= EE * F4) return;
    int e = tid / F4;
    int f = tid - e * F4;
    reinterpret_cast<float4*>(&E[(long long)dst[e] * FIN])[f] = make_float4(0.f, 0.f, 0.f, 0.f);
}

// ---------------- edge scatter: E[dst] += norm * X[src]  (rows pre-zeroed) -----------

template<int FIN>
__global__ void edge_scatter_k(const int* __restrict__ src, const int* __restrict__ dst,
                               const float* __restrict__ nrm, const float* __restrict__ X,
                               float* __restrict__ E) {
    constexpr int F4 = FIN / 4;
    int tid = blockIdx.x * 256 + threadIdx.x;
    if (tid >= EE * F4) return;
    int e = tid / F4;
    int f = (tid - e * F4) * 4;
    float n = nrm[e];
    const float4 v = *reinterpret_cast<const float4*>(&X[(long long)src[e] * FIN + f]);
    float* a = &E[(long long)dst[e] * FIN + f];
    atomicAdd(a + 0, n * v.x);
    atomicAdd(a + 1, n * v.y);
    atomicAdd(a + 2, n * v.z);
    atomicAdd(a + 3, n * v.w);
}

// ---------- fused small GEMM: out = act((E?=touched + X/deg) @ W + b) ----------

template<int K, int FOUT, bool RELU>
__global__ __launch_bounds__(256) void gemm_small_k(
    const float* __restrict__ E, const float* __restrict__ X,
    const float* __restrict__ deg, const float* __restrict__ W,
    const float* __restrict__ bias, float* __restrict__ out) {
    constexpr int NPB = 256 / FOUT;     // nodes per block
    __shared__ float Ws[K * FOUT];
    __shared__ float As[NPB][K];
    __shared__ float bs[FOUT];
    int tid = threadIdx.x;
    for (int i = tid; i < K * FOUT / 4; i += 256)
        reinterpret_cast<float4*>(Ws)[i] = reinterpret_cast<const float4*>(W)[i];
    if (tid < FOUT) bs[tid] = bias[tid];
    int node0 = blockIdx.x * NPB;
    for (int i = tid; i < NPB * (K / 4); i += 256) {
        int r = i / (K / 4);
        int kk = (i - r * (K / 4)) * 4;
        int g = node0 + r;
        float4 v = make_float4(0.f, 0.f, 0.f, 0.f);
        if (g < NN) {
            float dg = deg[g];
            float s = 1.0f / dg;
            float4 xv = *reinterpret_cast<const float4*>(&X[(long long)g * K + kk]);
            v = make_float4(xv.x * s, xv.y * s, xv.z * s, xv.w * s);
            if (dg != 1.0f) {   // node received edge messages -> E row is valid
                float4 ev = *reinterpret_cast<const float4*>(&E[(long long)g * K + kk]);
                v.x += ev.x; v.y += ev.y; v.z += ev.z; v.w += ev.w;
            }
        }
        *reinterpret_cast<float4*>(&As[r][kk]) = v;
    }
    __syncthreads();
    int ln = tid / FOUT;
    int n  = tid - ln * FOUT;
    int g = node0 + ln;
    if (g >= NN) return;
    float s = bs[n];
    #pragma unroll
    for (int k = 0; k < K; ++k)
        s = fmaf(As[ln][k], Ws[k * FOUT + n], s);
    if (RELU) s = fmaxf(s, 0.f);
    out[(long long)g * FOUT + n] = s;
}

// ---------------- W4 [64][2048] fp32 -> wthi, wtlo [2048][64] bf16 ----------------

__global__ void convert_wt_k(const float* __restrict__ W4,
                             ushort* __restrict__ wthi, ushort* __restrict__ wtlo) {
    int i = blockIdx.x * 256 + threadIdx.x;
    if (i >= 64 * 2048) return;
    int k = i >> 11;
    int c = i & 2047;
    float x = W4[i];
    ushort h = f2bf(x);
    ushort l = f2bf(x - bf2f(h));
    wthi[c * 64 + k] = h;
    wtlo[c * 64 + k] = l;
}

// ---------------- big GEMM: out[N,2048] = (E + H/deg)[N,64] @ W[64,2048] + b ----------
// Swapped MFMA operands (A-slot = W^T, B-slot = node) -> D: col(lane&15)=node,
// row(reg)=out-col.  Per 128-col group: ALL 32 W-fragment b128 loads issued into a
// register array BEFORE the MFMA loop (breaks per-tile load-latency serialization;
// needs ~170 VGPRs -> __launch_bounds__(256,1)).  LDS-staged coalesced epilogue.

__global__ __launch_bounds__(256, 1) void gemm_big_k(
    const float* __restrict__ E, const float* __restrict__ H,
    const float* __restrict__ deg,
    const ushort* __restrict__ wthi, const ushort* __restrict__ wtlo,
    const float* __restrict__ bias, float* __restrict__ out) {
    __shared__ float lds[4][16][128];   // 32 KB, wave-private patches
    int lane = threadIdx.x & 63;
    int wv   = threadIdx.x >> 6;
    int rl   = lane & 15;
    int kg   = lane >> 4;
    int node = blockIdx.y * 64 + wv * 16 + rl;
    bool valid = node < NN;

    // ---- prologue: build node fragments (hi/lo split in-register) ----
    bf16x8 nb_hi[2], nb_lo[2];
    {
        float v[2][8];
        if (valid) {
            float dg = deg[node];
            float s = 1.0f / dg;
            const float* h0 = H + (long long)node * 64 + kg * 8;
            #pragma unroll
            for (int f = 0; f < 2; ++f) {
                float4 ha = *reinterpret_cast<const float4*>(h0 + f * 32);
                float4 hb = *reinterpret_cast<const float4*>(h0 + f * 32 + 4);
                v[f][0] = ha.x * s; v[f][1] = ha.y * s; v[f][2] = ha.z * s; v[f][3] = ha.w * s;
                v[f][4] = hb.x * s; v[f][5] = hb.y * s; v[f][6] = hb.z * s; v[f][7] = hb.w * s;
            }
            if (dg != 1.0f) {   // E row valid only for edge-touched nodes
                const float* e0 = E + (long long)node * 64 + kg * 8;
                #pragma unroll
                for (int f = 0; f < 2; ++f) {
                    float4 ea = *reinterpret_cast<const float4*>(e0 + f * 32);
                    float4 eb = *reinterpret_cast<const float4*>(e0 + f * 32 + 4);
                    v[f][0] += ea.x; v[f][1] += ea.y; v[f][2] += ea.z; v[f][3] += ea.w;
                    v[f][4] += eb.x; v[f][5] += eb.y; v[f][6] += eb.z; v[f][7] += eb.w;
                }
            }
        } else {
            #pragma unroll
            for (int f = 0; f < 2; ++f)
                #pragma unroll
                for (int i = 0; i < 8; ++i) v[f][i] = 0.f;
        }
        #pragma unroll
        for (int f = 0; f < 2; ++f) {
            ushort8 h8, l8;
            #pragma unroll
            for (int i = 0; i < 8; ++i) {
                unsigned u = __float_as_uint(v[f][i]) & 0xFFFF0000u;  // hi = truncate
                h8[i] = (unsigned short)(u >> 16);
                l8[i] = f2bf(v[f][i] - __uint_as_float(u));
            }
            nb_hi[f] = __builtin_bit_cast(bf16x8, h8);
            nb_lo[f] = __builtin_bit_cast(bf16x8, l8);
        }
    }

    int cbase = blockIdx.x * 512;
    int grow_base = blockIdx.y * 64 + wv * 16;

    for (int g = 0; g < 4; ++g) {
        // ---- batch-issue all 32 W-fragment loads for this 128-col group ----
        bf16x8 wh0[8], wh1[8], wl0[8], wl1[8];
        #pragma unroll
        for (int tl = 0; tl < 8; ++tl) {
            int wc = cbase + g * 128 + tl * 16 + rl;
            const ushort* ph = wthi + wc * 64 + kg * 8;
            const ushort* pl = wtlo + wc * 64 + kg * 8;
            wh0[tl] = *reinterpret_cast<const bf16x8*>(ph);
            wh1[tl] = *reinterpret_cast<const bf16x8*>(ph + 32);
            wl0[tl] = *reinterpret_cast<const bf16x8*>(pl);
            wl1[tl] = *reinterpret_cast<const bf16x8*>(pl + 32);
        }
        // ---- MFMA loop over the 8 tiles (graduated vmcnt waits) ----
        #pragma unroll
        for (int tl = 0; tl < 8; ++tl) {
            int cb = cbase + g * 128 + tl * 16;
            floatx4 acc = *reinterpret_cast<const floatx4*>(&bias[cb + kg * 4]);
            acc = __builtin_amdgcn_mfma_f32_16x16x32_bf16(wh0[tl], nb_hi[0], acc, 0, 0, 0);
            acc = __builtin_amdgcn_mfma_f32_16x16x32_bf16(wh0[tl], nb_lo[0], acc, 0, 0, 0);
            acc = __builtin_amdgcn_mfma_f32_16x16x32_bf16(wl0[tl], nb_hi[0], acc, 0, 0, 0);
            acc = __builtin_amdgcn_mfma_f32_16x16x32_bf16(wh1[tl], nb_hi[1], acc, 0, 0, 0);
            acc = __builtin_amdgcn_mfma_f32_16x16x32_bf16(wh1[tl], nb_lo[1], acc, 0, 0, 0);
            acc = __builtin_amdgcn_mfma_f32_16x16x32_bf16(wl1[tl], nb_hi[1], acc, 0, 0, 0);
            int c4w = (tl * 4 + kg) ^ (rl & 7);
            *reinterpret_cast<floatx4*>(&lds[wv][rl][c4w * 4]) = acc;
        }
        // ---- flush: coalesced 512B-per-row segments, 2 rows per wave-store ----
        int rhalf = lane >> 5;
        int c4r   = lane & 31;
        #pragma unroll
        for (int rr = 0; rr < 8; ++rr) {
            int r = rr * 2 + rhalf;
            int cc4 = c4r ^ (r & 7);
            floatx4 v = *reinterpret_cast<const floatx4*>(&lds[wv][r][cc4 * 4]);
            int grow = grow_base + r;
            if (grow < NN)
                nt_store4(&out[(long long)grow * 2048 + cbase + g * 128 + c4r * 4], v);
        }
    }
}

// ---------------- launch ----------------

extern "C" void kernel_launch(void* const* d_in, const int* in_sizes, int n_in,
                              void* d_out, int out_size, void* d_ws, size_t ws_size,
                              hipStream_t stream) {
    const int*   edge_index = (const int*)d_in[0];   // [2, EE]
    const int*   src = edge_index;
    const int*   dst = edge_index + EE;
    const float* ew  = (const float*)d_in[1];
    const float* emb = (const float*)d_in[2];        // [NN,32]
    const float* W1  = (const float*)d_in[3];        // [32,64]
    const float* b1  = (const float*)d_in[4];
    const float* W2  = (const float*)d_in[5];        // [64,32]
    const float* b2  = (const float*)d_in[6];
    const float* W3  = (const float*)d_in[7];        // [32,64]
    const float* b3  = (const float*)d_in[8];
    const float* W4  = (const float*)d_in[9];        // [64,2048]
    const float* b4  = (const float*)d_in[10];

    float* out = (float*)d_out;                      // recon_x [NN,2048]
    float* z   = out + Z_OFF;                        // z [NN,32]

    float* ws   = (float*)d_ws;
    float* deg  = ws;                                // NN floats (pad 51684)
    float* nrm  = ws + 51684;                        // EE floats
    float* Ebuf = ws + 53732;                        // NN*64 floats (edge accum)
    float* t1   = Ebuf + 3307584;                    // NN*64 floats (layer output)
    ushort* wthi = (ushort*)(t1 + 3307584);          // 2048*64 ushorts
    ushort* wtlo = wthi + 2048 * 64;

    // normalization (shared by all 4 layers)
    deg_init_k<<<(NN + 255) / 256, 256, 0, stream>>>(deg);
    deg_scatter_k<<<(EE + 255) / 256, 256, 0, stream>>>(dst, ew, deg);
    norm_edge_k<<<(EE + 255) / 256, 256, 0, stream>>>(src, dst, ew, deg, nrm);

    // Layer 1: x1 = relu((E + emb/deg) @ W1 + b1) in t1[N,64]
    zero_rows_k<32><<<(EE * 8 + 255) / 256, 256, 0, stream>>>(dst, Ebuf);
    edge_scatter_k<32><<<(EE * 8 + 255) / 256, 256, 0, stream>>>(src, dst, nrm, emb, Ebuf);
    gemm_small_k<32, 64, true><<<(NN + 3) / 4, 256, 0, stream>>>(Ebuf, emb, deg, W1, b1, t1);

    // Layer 2: z = relu((E + x1/deg) @ W2 + b2) in d_out z-region [N,32]
    zero_rows_k<64><<<(EE * 16 + 255) / 256, 256, 0, stream>>>(dst, Ebuf);
    edge_scatter_k<64><<<(EE * 16 + 255) / 256, 256, 0, stream>>>(src, dst, nrm, t1, Ebuf);
    gemm_small_k<64, 32, true><<<(NN + 7) / 8, 256, 0, stream>>>(Ebuf, t1, deg, W2, b2, z);

    // Layer 3: h = relu((E + z/deg) @ W3 + b3) in t1[N,64]
    zero_rows_k<32><<<(EE * 8 + 255) / 256, 256, 0, stream>>>(dst, Ebuf);
    edge_scatter_k<32><<<(EE * 8 + 255) / 256, 256, 0, stream>>>(src, dst, nrm, z, Ebuf);
    gemm_small_k<32, 64, true><<<(NN + 3) / 4, 256, 0, stream>>>(Ebuf, z, deg, W3, b3, t1);

    // Layer 4: recon = (E + h/deg) @ W4 + b4 in d_out [N,2048]
    zero_rows_k<64><<<(EE * 16 + 255) / 256, 256, 0, stream>>>(dst, Ebuf);
    edge_scatter_k<64><<<(EE * 16 + 255) / 256, 256, 0, stream>>>(src, dst, nrm, t1, Ebuf);
    convert_wt_k<<<(64 * 2048 + 255) / 256, 256, 0, stream>>>(W4, wthi, wtlo);
    gemm_big_k<<<dim3(4, 808), 256, 0, stream>>>(Ebuf, t1, deg, wthi, wtlo, b4, out);
}